// Round 7
// baseline (127.005 us; speedup 1.0000x reference)
//
#include <hip/hip_runtime.h>
#include <hip/hip_fp16.h>

#define D_MODEL 128
#define NB 4
#define NN 512

typedef _Float16 f16;
typedef _Float16 f16x8 __attribute__((ext_vector_type(8)));
typedef float f32x4 __attribute__((ext_vector_type(4)));

// ---------------------------------------------------------------------------
// Kernel 1: Hi = x @ W1[:128] + b1, Hj = x @ W1[128:]  (fp16), plus W2 prepack
// into mfma A-fragment layout.  blocks 0..511: 4 rows each.  block 512: pack.
// ---------------------------------------------------------------------------
__global__ __launch_bounds__(256) void prep_kernel(
    const float* __restrict__ x,    // [B*N,128]
    const float* __restrict__ W1,   // [256,128]
    const float* __restrict__ b1,   // [128]
    const float* __restrict__ W2,   // [128,64]
    f16* __restrict__ Hi, f16* __restrict__ Hj, f16* __restrict__ W2p)
{
    const int blk = blockIdx.x;
    const int t = threadIdx.x;
    if (blk < 512) {
        const int r0 = blk * 4;                  // global row (b*N+n)
        __shared__ float xs[4][128];
        #pragma unroll
        for (int idx = t; idx < 4 * 128; idx += 256)
            xs[idx >> 7][idx & 127] = x[(size_t)r0 * 128 + idx];
        __syncthreads();

        const int isJ = t >> 7;                  // 0 -> Hi, 1 -> Hj
        const int k = t & 127;
        const float* wcol = W1 + (isJ ? 128 * 128 : 0) + k;
        float acc[4] = {0.f, 0.f, 0.f, 0.f};
        #pragma unroll 4
        for (int d4 = 0; d4 < 32; d4++) {
            f32x4 xv[4];
            #pragma unroll
            for (int r = 0; r < 4; r++) xv[r] = *(const f32x4*)&xs[r][d4 * 4];
            #pragma unroll
            for (int dd = 0; dd < 4; dd++) {
                float w = wcol[(d4 * 4 + dd) * 128];
                #pragma unroll
                for (int r = 0; r < 4; r++) acc[r] = fmaf(xv[r][dd], w, acc[r]);
            }
        }
        const float bb = isJ ? 0.f : b1[k];
        f16* dst = isJ ? Hj : Hi;
        #pragma unroll
        for (int r = 0; r < 4; r++)
            dst[(size_t)(r0 + r) * 128 + k] = (f16)(acc[r] + bb);
    } else {
        // W2 prepack (A-operand layout for W2^T tiles):
        // W2p[((kt*4+nt)*64 + lane)*8 + jj] = W2[kt*32+8*(lane>>4)+jj][nt*16+(lane&15)]
        for (int slot = t; slot < 16 * 64; slot += 256) {
            const int lane = slot & 63;
            const int fidx = slot >> 6;          // kt*4+nt
            const int kt = fidx >> 2, nt = fidx & 3;
            const int krow = kt * 32 + 8 * (lane >> 4);
            const int col = nt * 16 + (lane & 15);
            #pragma unroll
            for (int j = 0; j < 8; j++)
                W2p[(size_t)slot * 8 + j] = (f16)W2[(krow + j) * 64 + col];
        }
    }
}

// ---------------------------------------------------------------------------
// Kernel 2: per wave: 16 j's x 8 i's.  s = relu(Hi[i]+Hj[j]) as B operand,
// A = W2^T fragments PINNED in VGPRs (asm) so the compiler cannot re-load
// them from L2 every iteration (R5's hidden 1 GB L2 stream).
// ---------------------------------------------------------------------------
__global__ __launch_bounds__(256, 4) void pair_kernel(
    const f16* __restrict__ Hi, const f16* __restrict__ Hj,
    const f16* __restrict__ W2p,
    const float* __restrict__ b2, const float* __restrict__ W3,
    const float* __restrict__ b3p, float* __restrict__ out)
{
    const int lane = threadIdx.x & 63;
    const int wave = threadIdx.x >> 6;

    // bijective XCD swizzle (2048 % 8 == 0): each XCD gets a contiguous
    // logical chunk -> shared Hi/Hj panels stay in its L2.
    const int logical = (blockIdx.x & 7) * 256 + (blockIdx.x >> 3);
    const int jg4 = logical & 7;
    const int ic  = (logical >> 3) & 63;
    const int b   = logical >> 9;
    const int j0 = (jg4 * 4 + wave) * 16;
    const int i0 = ic * 8;

    const int lrow = lane & 15;
    const int lgrp = lane >> 4;

    // W2^T fragments (A-operand) — load once, pin in registers.
    f16x8 w2f[4][4];
    #pragma unroll
    for (int kt = 0; kt < 4; kt++)
        #pragma unroll
        for (int nt = 0; nt < 4; nt++) {
            w2f[kt][nt] = *(const f16x8*)(W2p + (size_t)((kt * 4 + nt) * 64 + lane) * 8);
            asm volatile("" : "+v"(w2f[kt][nt]));
        }

    // Hj fragments (B-operand layout: col=lrow -> j, k=8*lgrp+jj) — pinned.
    const f16* hjbase = Hj + (size_t)(b * NN + j0 + lrow) * 128 + 8 * lgrp;
    f16x8 hjf[4];
    #pragma unroll
    for (int kt = 0; kt < 4; kt++) {
        hjf[kt] = *(const f16x8*)(hjbase + kt * 32);
        asm volatile("" : "+v"(hjf[kt]));
    }

    // per-lane m = nt*16 + 4*lgrp + r
    f32x4 b2v[4], w3v[4];
    #pragma unroll
    for (int nt = 0; nt < 4; nt++) {
        b2v[nt] = *(const f32x4*)(b2 + nt * 16 + 4 * lgrp);
        w3v[nt] = *(const f32x4*)(W3 + nt * 16 + 4 * lgrp);
    }
    const float b3 = b3p[0];

    const f16* hibase = Hi + (size_t)(b * NN + i0) * 128 + 8 * lgrp;
    float* orow = out + ((size_t)b * NN + i0) * NN + j0 + lrow;

    const f16x8 zero8 = (f16x8)(f16)0;

    #pragma unroll 2
    for (int ii = 0; ii < 8; ii++) {
        f16x8 hif[4];
        #pragma unroll
        for (int kt = 0; kt < 4; kt++)
            hif[kt] = *(const f16x8*)(hibase + ii * 128 + kt * 32);

        f32x4 accD[4];
        #pragma unroll
        for (int nt = 0; nt < 4; nt++) accD[nt] = (f32x4)(0.0f);

        #pragma unroll
        for (int kt = 0; kt < 4; kt++) {
            f16x8 s = hif[kt] + hjf[kt];                     // v_pk_add_f16 x4
            s = __builtin_elementwise_max(s, zero8);         // v_pk_max_f16 x4
            #pragma unroll
            for (int nt = 0; nt < 4; nt++)
                accD[nt] = __builtin_amdgcn_mfma_f32_16x16x32_f16(w2f[kt][nt], s, accD[nt], 0, 0, 0);
        }

        // epilogue: all 16 m-values for this lane's j are in-lane
        float acc = 0.f;
        #pragma unroll
        for (int nt = 0; nt < 4; nt++) {
            #pragma unroll
            for (int r = 0; r < 4; r++) {
                float h = fmaxf(accD[nt][r] + b2v[nt][r], 0.f);
                acc = fmaf(h, w3v[nt][r], acc);
            }
        }
        acc += __shfl_xor(acc, 16, 64);
        acc += __shfl_xor(acc, 32, 64);
        float sg = __builtin_amdgcn_rcpf(1.f + __expf(-(acc + b3)));
        if (lgrp == 0)
            __builtin_nontemporal_store(sg, orow + (size_t)ii * NN);
    }
}

extern "C" void kernel_launch(void* const* d_in, const int* in_sizes, int n_in,
                              void* d_out, int out_size, void* d_ws, size_t ws_size,
                              hipStream_t stream) {
    const float* x  = (const float*)d_in[0];   // [4,512,128]
    const float* W1 = (const float*)d_in[1];   // [256,128]
    const float* b1 = (const float*)d_in[2];   // [128]
    const float* W2 = (const float*)d_in[3];   // [128,64]
    const float* b2 = (const float*)d_in[4];   // [64]
    const float* W3 = (const float*)d_in[5];   // [64,1]
    const float* b3 = (const float*)d_in[6];   // [1]
    float* out = (float*)d_out;                // [4,512,512]

    f16* Hi  = (f16*)d_ws;                     // 262144 halves
    f16* Hj  = Hi + (size_t)NB * NN * 128;     // 262144 halves
    f16* W2p = Hj + (size_t)NB * NN * 128;     // 8192 halves

    prep_kernel<<<513, 256, 0, stream>>>(x, W1, b1, W2, Hi, Hj, W2p);
    pair_kernel<<<2048, 256, 0, stream>>>(Hi, Hj, W2p, b2, W3, b3, out);
}

// Round 13
// 121.486 us; speedup vs baseline: 1.0454x; 1.0454x over previous
//
#include <hip/hip_runtime.h>
#include <hip/hip_fp16.h>

#define D_MODEL 128
#define NB 4
#define NN 512

typedef _Float16 f16;
typedef _Float16 f16x8 __attribute__((ext_vector_type(8)));
typedef float f32x4 __attribute__((ext_vector_type(4)));

// ---------------------------------------------------------------------------
// Kernel 1: Hi = x @ W1[:128] + b1, Hj = x @ W1[128:]  (fp16), plus W2 prepack
// into mfma A-fragment layout.  blocks 0..255: 8 rows each.  block 256: pack.
// ---------------------------------------------------------------------------
__global__ __launch_bounds__(256) void prep_kernel(
    const float* __restrict__ x,    // [B*N,128]
    const float* __restrict__ W1,   // [256,128]
    const float* __restrict__ b1,   // [128]
    const float* __restrict__ W2,   // [128,64]
    f16* __restrict__ Hi, f16* __restrict__ Hj, f16* __restrict__ W2p)
{
    const int blk = blockIdx.x;
    const int t = threadIdx.x;
    if (blk < 256) {
        const int r0 = blk * 8;                  // global row (b*N+n)
        __shared__ float xs[8][128];
        #pragma unroll
        for (int idx = t; idx < 8 * 128; idx += 256)
            xs[idx >> 7][idx & 127] = x[(size_t)r0 * 128 + idx];
        __syncthreads();

        const int isJ = t >> 7;                  // 0 -> Hi, 1 -> Hj
        const int k = t & 127;
        const float* wcol = W1 + (isJ ? 128 * 128 : 0) + k;
        float acc[8] = {0.f, 0.f, 0.f, 0.f, 0.f, 0.f, 0.f, 0.f};
        #pragma unroll 4
        for (int d4 = 0; d4 < 32; d4++) {
            f32x4 xv[8];
            #pragma unroll
            for (int r = 0; r < 8; r++) xv[r] = *(const f32x4*)&xs[r][d4 * 4];
            #pragma unroll
            for (int dd = 0; dd < 4; dd++) {
                float w = wcol[(d4 * 4 + dd) * 128];
                #pragma unroll
                for (int r = 0; r < 8; r++) acc[r] = fmaf(xv[r][dd], w, acc[r]);
            }
        }
        const float bb = isJ ? 0.f : b1[k];
        f16* dst = isJ ? Hj : Hi;
        #pragma unroll
        for (int r = 0; r < 8; r++)
            dst[(size_t)(r0 + r) * 128 + k] = (f16)(acc[r] + bb);
    } else {
        // W2 prepack (A-operand layout for W2^T tiles):
        // W2p[((kt*4+nt)*64 + lane)*8 + jj] = W2[kt*32+8*(lane>>4)+jj][nt*16+(lane&15)]
        for (int slot = t; slot < 16 * 64; slot += 256) {
            const int lane = slot & 63;
            const int fidx = slot >> 6;          // kt*4+nt
            const int kt = fidx >> 2, nt = fidx & 3;
            const int krow = kt * 32 + 8 * (lane >> 4);
            const int col = nt * 16 + (lane & 15);
            #pragma unroll
            for (int j = 0; j < 8; j++)
                W2p[(size_t)slot * 8 + j] = (f16)W2[(krow + j) * 64 + col];
        }
    }
}

// ---------------------------------------------------------------------------
// Kernel 2: per block: 16 i's x 64 j's (4 waves x 16 j).  s = relu(Hi+Hj) as
// B operand, A = W2^T fragments (L1-resident, compiler may remat — cheap).
// Epilogue: in-lane m-reduction + 2 shfl allreduce; results staged in LDS and
// stored as full 256B rows of float4 (clean write path — R5/R6's scalar /
// nontemporal stores caused 5-10x HBM write inflation).
// ---------------------------------------------------------------------------
__global__ __launch_bounds__(256, 4) void pair_kernel(
    const f16* __restrict__ Hi, const f16* __restrict__ Hj,
    const f16* __restrict__ W2p,
    const float* __restrict__ b2, const float* __restrict__ W3,
    const float* __restrict__ b3p, float* __restrict__ out)
{
    const int lane = threadIdx.x & 63;
    const int wave = threadIdx.x >> 6;

    // bijective XCD swizzle (1024 = 8 * 128): each XCD gets a contiguous
    // logical chunk -> shared Hi/Hj panels stay in its L2.
    const int logical = (blockIdx.x & 7) * 128 + (blockIdx.x >> 3);
    const int jg = logical & 7;                  // j-block of 64
    const int ic = (logical >> 3) & 31;          // i-block of 16
    const int b  = logical >> 8;
    const int jblk = jg * 64;
    const int j0 = jblk + wave * 16;
    const int i0 = ic * 16;

    const int lrow = lane & 15;
    const int lgrp = lane >> 4;

    __shared__ float tile[16][65];               // 16 i x 64 j staging (+pad)

    // W2^T fragments (A-operand)
    f16x8 w2f[4][4];
    #pragma unroll
    for (int kt = 0; kt < 4; kt++)
        #pragma unroll
        for (int nt = 0; nt < 4; nt++)
            w2f[kt][nt] = *(const f16x8*)(W2p + (size_t)((kt * 4 + nt) * 64 + lane) * 8);

    // Hj fragments (B-operand layout: col=lrow -> j, k=8*lgrp+jj)
    const f16* hjbase = Hj + (size_t)(b * NN + j0 + lrow) * 128 + 8 * lgrp;
    f16x8 hjf[4];
    #pragma unroll
    for (int kt = 0; kt < 4; kt++)
        hjf[kt] = *(const f16x8*)(hjbase + kt * 32);

    // per-lane m = nt*16 + 4*lgrp + r
    f32x4 b2v[4], w3v[4];
    #pragma unroll
    for (int nt = 0; nt < 4; nt++) {
        b2v[nt] = *(const f32x4*)(b2 + nt * 16 + 4 * lgrp);
        w3v[nt] = *(const f32x4*)(W3 + nt * 16 + 4 * lgrp);
    }
    const float b3 = b3p[0];

    const f16* hibase = Hi + (size_t)(b * NN + i0) * 128 + 8 * lgrp;

    const f16x8 zero8 = (f16x8)(f16)0;

    #pragma unroll 2
    for (int ii = 0; ii < 16; ii++) {
        f16x8 hif[4];
        #pragma unroll
        for (int kt = 0; kt < 4; kt++)
            hif[kt] = *(const f16x8*)(hibase + ii * 128 + kt * 32);

        f32x4 accD[4];
        #pragma unroll
        for (int nt = 0; nt < 4; nt++) accD[nt] = (f32x4)(0.0f);

        #pragma unroll
        for (int kt = 0; kt < 4; kt++) {
            f16x8 s = hif[kt] + hjf[kt];                     // v_pk_add_f16 x4
            s = __builtin_elementwise_max(s, zero8);         // v_pk_max_f16 x4
            #pragma unroll
            for (int nt = 0; nt < 4; nt++)
                accD[nt] = __builtin_amdgcn_mfma_f32_16x16x32_f16(w2f[kt][nt], s, accD[nt], 0, 0, 0);
        }

        // epilogue: 16 m-values in-lane, then allreduce over the 4 lgrp groups
        float acc = 0.f;
        #pragma unroll
        for (int nt = 0; nt < 4; nt++) {
            #pragma unroll
            for (int r = 0; r < 4; r++) {
                float h = fmaxf(accD[nt][r] + b2v[nt][r], 0.f);
                acc = fmaf(h, w3v[nt][r], acc);
            }
        }
        acc += __shfl_xor(acc, 16, 64);
        acc += __shfl_xor(acc, 32, 64);
        float sg = __builtin_amdgcn_rcpf(1.f + __expf(-(acc + b3)));
        if (lgrp == 0)
            tile[ii][wave * 16 + lrow] = sg;
    }

    __syncthreads();

    // block-wide coalesced store: 16 rows x 256 B (float4 per thread)
    {
        const int row = threadIdx.x >> 4;        // 0..15
        const int c4  = threadIdx.x & 15;        // 0..15
        f32x4 v = *(const f32x4*)&tile[row][c4 * 4];
        *(f32x4*)(out + ((size_t)(b * NN + i0 + row)) * NN + jblk + c4 * 4) = v;
    }
}

extern "C" void kernel_launch(void* const* d_in, const int* in_sizes, int n_in,
                              void* d_out, int out_size, void* d_ws, size_t ws_size,
                              hipStream_t stream) {
    const float* x  = (const float*)d_in[0];   // [4,512,128]
    const float* W1 = (const float*)d_in[1];   // [256,128]
    const float* b1 = (const float*)d_in[2];   // [128]
    const float* W2 = (const float*)d_in[3];   // [128,64]
    const float* b2 = (const float*)d_in[4];   // [64]
    const float* W3 = (const float*)d_in[5];   // [64,1]
    const float* b3 = (const float*)d_in[6];   // [1]
    float* out = (float*)d_out;                // [4,512,512]

    f16* Hi  = (f16*)d_ws;                     // 262144 halves
    f16* Hj  = Hi + (size_t)NB * NN * 128;     // 262144 halves
    f16* W2p = Hj + (size_t)NB * NN * 128;     // 8192 halves

    prep_kernel<<<257, 256, 0, stream>>>(x, W1, b1, W2, Hi, Hj, W2p);
    pair_kernel<<<1024, 256, 0, stream>>>(Hi, Hj, W2p, b2, W3, b3, out);
}

// Round 15
// 116.454 us; speedup vs baseline: 1.0906x; 1.0432x over previous
//
#include <hip/hip_runtime.h>
#include <hip/hip_fp16.h>

#define D_MODEL 128
#define NB 4
#define NN 512

typedef _Float16 f16;
typedef _Float16 f16x8 __attribute__((ext_vector_type(8)));
typedef float f32x4 __attribute__((ext_vector_type(4)));

// ---------------------------------------------------------------------------
// Kernel 1: Hi = x @ W1[:128] + b1, Hj = x @ W1[128:]  (fp16), plus W2 prepack
// into mfma_f32_16x16x32_f16 B-fragment layout.
// blocks 0..127: 16 rows each of Hi/Hj.  block 128: W2 prepack.
// (verbatim from R4 — the best-measured round)
// ---------------------------------------------------------------------------
__global__ __launch_bounds__(256) void prep_kernel(
    const float* __restrict__ x,    // [B*N,128]
    const float* __restrict__ W1,   // [256,128]
    const float* __restrict__ b1,   // [128]
    const float* __restrict__ W2,   // [128,64]
    f16* __restrict__ Hi, f16* __restrict__ Hj, f16* __restrict__ W2p)
{
    const int blk = blockIdx.x;
    const int t = threadIdx.x;
    if (blk < 128) {
        const int r0 = blk * 16;                 // global row (b*N+n)
        __shared__ float xs[16][128];
        for (int idx = t; idx < 16 * 128; idx += 256)
            xs[idx >> 7][idx & 127] = x[(size_t)r0 * 128 + idx];
        __syncthreads();

        const int isJ = t >> 7;                  // 0 -> Hi, 1 -> Hj
        const int k = t & 127;
        const float* wcol = W1 + (isJ ? 128 * 128 : 0) + k;
        float acc[16];
        #pragma unroll
        for (int r = 0; r < 16; r++) acc[r] = 0.f;
        for (int d = 0; d < 128; d++) {
            float w = wcol[d * 128];
            #pragma unroll
            for (int r = 0; r < 16; r++) acc[r] = fmaf(xs[r][d], w, acc[r]);
        }
        const float bb = isJ ? 0.f : b1[k];
        f16* dst = isJ ? Hj : Hi;
        #pragma unroll
        for (int r = 0; r < 16; r++)
            dst[(size_t)(r0 + r) * 128 + k] = (f16)(acc[r] + bb);
    } else {
        // W2 prepack: W2p[((kt*4+nt)*64 + lane)*8 + j] = W2[kt*32+8*(lane>>4)+j][nt*16+(lane&15)]
        for (int slot = t; slot < 16 * 64; slot += 256) {
            const int lane = slot & 63;
            const int fidx = slot >> 6;          // kt*4+nt
            const int kt = fidx >> 2, nt = fidx & 3;
            const int krow = kt * 32 + 8 * (lane >> 4);
            const int col = nt * 16 + (lane & 15);
            #pragma unroll
            for (int j = 0; j < 8; j++)
                W2p[(size_t)slot * 8 + j] = (f16)W2[(krow + j) * 64 + col];
        }
    }
}

// ---------------------------------------------------------------------------
// Kernel 2: R4 structure verbatim (operand order A=s, B=W2 frag; butterfly
// reduce; direct 64B float4 stores — measured WRITE_SIZE exactly = output).
// ONE change vs R4: i-chunk 32 -> 16, grid 512 -> 1024, to lift the measured
// occupancy/latency limit (R4: 2 blocks/CU, Occupancy 19%, all pipes idle).
// ---------------------------------------------------------------------------
__global__ __launch_bounds__(256) void pair_kernel(
    const f16* __restrict__ Hi, const f16* __restrict__ Hj,
    const f16* __restrict__ W2p,
    const float* __restrict__ b2, const float* __restrict__ W3,
    const float* __restrict__ b3p, float* __restrict__ out)
{
    const int lane = threadIdx.x & 63;
    const int wave = threadIdx.x >> 6;
    const int bid = blockIdx.x;                  // 4(b) * 32(ic) * 8(jg4)
    const int jg4 = bid & 7;
    const int ic  = (bid >> 3) & 31;
    const int b   = bid >> 8;
    const int j0 = (jg4 * 4 + wave) * 16;
    const int i0 = ic * 16;

    const int lrow = lane & 15;
    const int lgrp = lane >> 4;

    // W2 fragments (B-operand)
    f16x8 w2f[4][4];
    #pragma unroll
    for (int kt = 0; kt < 4; kt++)
        #pragma unroll
        for (int nt = 0; nt < 4; nt++)
            w2f[kt][nt] = *(const f16x8*)(W2p + (size_t)((kt * 4 + nt) * 64 + lane) * 8);

    // Hj fragments (A-operand layout: row=lrow -> j, k=8*lgrp+jj)
    const f16* hjbase = Hj + (size_t)(b * NN + j0 + lrow) * 128 + 8 * lgrp;
    f16x8 hjf[4];
    #pragma unroll
    for (int kt = 0; kt < 4; kt++)
        hjf[kt] = *(const f16x8*)(hjbase + kt * 32);

    float b2v[4], w3v[4];
    #pragma unroll
    for (int nt = 0; nt < 4; nt++) {
        b2v[nt] = b2[nt * 16 + lrow];
        w3v[nt] = W3[nt * 16 + lrow];
    }
    const float b3 = b3p[0];

    const f16* hibase = Hi + (size_t)(b * NN + i0) * 128 + 8 * lgrp;
    float* obase = out + ((size_t)b * NN + i0) * NN + j0;

    const f16x8 zero8 = (f16x8)(f16)0;

    #pragma unroll 2
    for (int ii = 0; ii < 16; ii++) {
        f16x8 hif[4];
        #pragma unroll
        for (int kt = 0; kt < 4; kt++)
            hif[kt] = *(const f16x8*)(hibase + ii * 128 + kt * 32);

        f32x4 accD[4];
        #pragma unroll
        for (int nt = 0; nt < 4; nt++) accD[nt] = (f32x4)(0.0f);

        #pragma unroll
        for (int kt = 0; kt < 4; kt++) {
            f16x8 s = hif[kt] + hjf[kt];                     // v_pk_add_f16 x4
            s = __builtin_elementwise_max(s, zero8);         // v_pk_max_f16 x4
            #pragma unroll
            for (int nt = 0; nt < 4; nt++)
                accD[nt] = __builtin_amdgcn_mfma_f32_16x16x32_f16(s, w2f[kt][nt], accD[nt], 0, 0, 0);
        }

        // epilogue: h2 = relu(D + b2); partial = h2 * W3; reduce over 16 lanes
        float acc[4] = {0.f, 0.f, 0.f, 0.f};
        #pragma unroll
        for (int nt = 0; nt < 4; nt++) {
            #pragma unroll
            for (int r = 0; r < 4; r++) {
                float h = fmaxf(accD[nt][r] + b2v[nt], 0.f);
                acc[r] = fmaf(h, w3v[nt], acc[r]);
            }
        }
        #pragma unroll
        for (int r = 0; r < 4; r++) {
            #pragma unroll
            for (int m = 1; m < 16; m <<= 1)
                acc[r] += __shfl_xor(acc[r], m, 64);
        }
        if (lrow == 0) {
            float4 o;
            float lg0 = acc[0] + b3, lg1 = acc[1] + b3, lg2 = acc[2] + b3, lg3 = acc[3] + b3;
            o.x = 1.f / (1.f + __expf(-lg0));
            o.y = 1.f / (1.f + __expf(-lg1));
            o.z = 1.f / (1.f + __expf(-lg2));
            o.w = 1.f / (1.f + __expf(-lg3));
            *(float4*)(obase + (size_t)ii * NN + lgrp * 4) = o;
        }
    }
}

extern "C" void kernel_launch(void* const* d_in, const int* in_sizes, int n_in,
                              void* d_out, int out_size, void* d_ws, size_t ws_size,
                              hipStream_t stream) {
    const float* x  = (const float*)d_in[0];   // [4,512,128]
    const float* W1 = (const float*)d_in[1];   // [256,128]
    const float* b1 = (const float*)d_in[2];   // [128]
    const float* W2 = (const float*)d_in[3];   // [128,64]
    const float* b2 = (const float*)d_in[4];   // [64]
    const float* W3 = (const float*)d_in[5];   // [64,1]
    const float* b3 = (const float*)d_in[6];   // [1]
    float* out = (float*)d_out;                // [4,512,512]

    f16* Hi  = (f16*)d_ws;                     // 262144 halves
    f16* Hj  = Hi + (size_t)NB * NN * 128;     // 262144 halves
    f16* W2p = Hj + (size_t)NB * NN * 128;     // 8192 halves

    prep_kernel<<<129, 256, 0, stream>>>(x, W1, b1, W2, Hi, Hj, W2p);
    pair_kernel<<<1024, 256, 0, stream>>>(Hi, Hj, W2p, b2, W3, b3, out);
}

// Round 18
// 112.216 us; speedup vs baseline: 1.1318x; 1.0378x over previous
//
#include <hip/hip_runtime.h>
#include <hip/hip_fp16.h>

#define D_MODEL 128
#define NB 4
#define NN 512

typedef _Float16 f16;
typedef _Float16 f16x8 __attribute__((ext_vector_type(8)));
typedef float f32x4 __attribute__((ext_vector_type(4)));

// ---------------------------------------------------------------------------
// Kernel 1: verbatim R4 (proven clean).  Hi = x@W1[:128]+b1, Hj = x@W1[128:]
// (fp16); W2 prepack into mfma fragment layout (works as A- or B-operand
// tile since the two maps are transposes).
// ---------------------------------------------------------------------------
__global__ __launch_bounds__(256) void prep_kernel(
    const float* __restrict__ x,    // [B*N,128]
    const float* __restrict__ W1,   // [256,128]
    const float* __restrict__ b1,   // [128]
    const float* __restrict__ W2,   // [128,64]
    f16* __restrict__ Hi, f16* __restrict__ Hj, f16* __restrict__ W2p)
{
    const int blk = blockIdx.x;
    const int t = threadIdx.x;
    if (blk < 128) {
        const int r0 = blk * 16;                 // global row (b*N+n)
        __shared__ float xs[16][128];
        for (int idx = t; idx < 16 * 128; idx += 256)
            xs[idx >> 7][idx & 127] = x[(size_t)r0 * 128 + idx];
        __syncthreads();

        const int isJ = t >> 7;                  // 0 -> Hi, 1 -> Hj
        const int k = t & 127;
        const float* wcol = W1 + (isJ ? 128 * 128 : 0) + k;
        float acc[16];
        #pragma unroll
        for (int r = 0; r < 16; r++) acc[r] = 0.f;
        for (int d = 0; d < 128; d++) {
            float w = wcol[d * 128];
            #pragma unroll
            for (int r = 0; r < 16; r++) acc[r] = fmaf(xs[r][d], w, acc[r]);
        }
        const float bb = isJ ? 0.f : b1[k];
        f16* dst = isJ ? Hj : Hi;
        #pragma unroll
        for (int r = 0; r < 16; r++)
            dst[(size_t)(r0 + r) * 128 + k] = (f16)(acc[r] + bb);
    } else {
        // W2p[((kt*4+nt)*64 + lane)*8 + jj] = W2[kt*32+8*(lane>>4)+jj][nt*16+(lane&15)]
        for (int slot = t; slot < 16 * 64; slot += 256) {
            const int lane = slot & 63;
            const int fidx = slot >> 6;          // kt*4+nt
            const int kt = fidx >> 2, nt = fidx & 3;
            const int krow = kt * 32 + 8 * (lane >> 4);
            const int col = nt * 16 + (lane & 15);
            #pragma unroll
            for (int j = 0; j < 8; j++)
                W2p[(size_t)slot * 8 + j] = (f16)W2[(krow + j) * 64 + col];
        }
    }
}

// ---------------------------------------------------------------------------
// Kernel 2: swapped operands — A = W2^T fragments, B = s = relu(Hi+Hj).
// D: col(lane&15)=j, row(4*lgrp+r) with tile nt -> m = nt*16+4*lgrp+r, so
// each lane reduces its 16 m-values IN-LANE and only 2 cross-lane ops
// (xor16+xor32) finish the sum — vs R4's 16 ds_bpermute per wave-ii (the
// per-CU DS-pipe serializer that made occupancy irrelevant).
// PLAIN __launch_bounds__(256): the (256,4) hint provably caused VGPR=64 +
// ~18 MB scratch spill traffic in R5/R6/R13.  Stores: 16 consecutive floats
// per wave (one coalesced 64B transaction).
// ---------------------------------------------------------------------------
__global__ __launch_bounds__(256) void pair_kernel(
    const f16* __restrict__ Hi, const f16* __restrict__ Hj,
    const f16* __restrict__ W2p,
    const float* __restrict__ b2, const float* __restrict__ W3,
    const float* __restrict__ b3p, float* __restrict__ out)
{
    const int lane = threadIdx.x & 63;
    const int wave = threadIdx.x >> 6;
    const int bid = blockIdx.x;                  // 4(b) * 32(ic) * 8(jg4)
    const int jg4 = bid & 7;
    const int ic  = (bid >> 3) & 31;
    const int b   = bid >> 8;
    const int j0 = (jg4 * 4 + wave) * 16;
    const int i0 = ic * 16;

    const int lrow = lane & 15;
    const int lgrp = lane >> 4;

    // W2^T fragments (A-operand): A[m=lane&15, k=kt*32+8*lgrp+jj]
    f16x8 w2f[4][4];
    #pragma unroll
    for (int kt = 0; kt < 4; kt++)
        #pragma unroll
        for (int nt = 0; nt < 4; nt++)
            w2f[kt][nt] = *(const f16x8*)(W2p + (size_t)((kt * 4 + nt) * 64 + lane) * 8);

    // Hj fragments (B-operand: col=lrow -> j, k=kt*32+8*lgrp+jj)
    const f16* hjbase = Hj + (size_t)(b * NN + j0 + lrow) * 128 + 8 * lgrp;
    f16x8 hjf[4];
    #pragma unroll
    for (int kt = 0; kt < 4; kt++)
        hjf[kt] = *(const f16x8*)(hjbase + kt * 32);

    // per-lane m = nt*16 + 4*lgrp + r  (16B-aligned f32x4 loads)
    f32x4 b2v[4], w3v[4];
    #pragma unroll
    for (int nt = 0; nt < 4; nt++) {
        b2v[nt] = *(const f32x4*)(b2 + nt * 16 + 4 * lgrp);
        w3v[nt] = *(const f32x4*)(W3 + nt * 16 + 4 * lgrp);
    }
    const float b3 = b3p[0];

    const f16* hibase = Hi + (size_t)(b * NN + i0) * 128 + 8 * lgrp;
    float* orow = out + ((size_t)b * NN + i0) * NN + j0 + lrow;

    const f16x8 zero8 = (f16x8)(f16)0;

    #pragma unroll 2
    for (int ii = 0; ii < 16; ii++) {
        f16x8 hif[4];
        #pragma unroll
        for (int kt = 0; kt < 4; kt++)
            hif[kt] = *(const f16x8*)(hibase + ii * 128 + kt * 32);

        f32x4 accD[4];
        #pragma unroll
        for (int nt = 0; nt < 4; nt++) accD[nt] = (f32x4)(0.0f);

        #pragma unroll
        for (int kt = 0; kt < 4; kt++) {
            f16x8 s = hif[kt] + hjf[kt];                     // v_pk_add_f16 x4
            s = __builtin_elementwise_max(s, zero8);         // v_pk_max_f16 x4
            #pragma unroll
            for (int nt = 0; nt < 4; nt++)
                accD[nt] = __builtin_amdgcn_mfma_f32_16x16x32_f16(w2f[kt][nt], s, accD[nt], 0, 0, 0);
        }

        // epilogue: 16 m-values in-lane, then 2 cross-lane steps over lgrp
        float acc = 0.f;
        #pragma unroll
        for (int nt = 0; nt < 4; nt++) {
            #pragma unroll
            for (int r = 0; r < 4; r++) {
                float h = fmaxf(accD[nt][r] + b2v[nt][r], 0.f);
                acc = fmaf(h, w3v[nt][r], acc);
            }
        }
        acc += __shfl_xor(acc, 16, 64);
        acc += __shfl_xor(acc, 32, 64);
        float sg = 1.f / (1.f + __expf(-(acc + b3)));
        if (lgrp == 0)
            orow[(size_t)ii * NN] = sg;          // 16 lanes -> one 64B txn
    }
}

extern "C" void kernel_launch(void* const* d_in, const int* in_sizes, int n_in,
                              void* d_out, int out_size, void* d_ws, size_t ws_size,
                              hipStream_t stream) {
    const float* x  = (const float*)d_in[0];   // [4,512,128]
    const float* W1 = (const float*)d_in[1];   // [256,128]
    const float* b1 = (const float*)d_in[2];   // [128]
    const float* W2 = (const float*)d_in[3];   // [128,64]
    const float* b2 = (const float*)d_in[4];   // [64]
    const float* W3 = (const float*)d_in[5];   // [64,1]
    const float* b3 = (const float*)d_in[6];   // [1]
    float* out = (float*)d_out;                // [4,512,512]

    f16* Hi  = (f16*)d_ws;                     // 262144 halves
    f16* Hj  = Hi + (size_t)NB * NN * 128;     // 262144 halves
    f16* W2p = Hj + (size_t)NB * NN * 128;     // 8192 halves

    prep_kernel<<<129, 256, 0, stream>>>(x, W1, b1, W2, Hi, Hj, W2p);
    pair_kernel<<<1024, 256, 0, stream>>>(Hi, Hj, W2p, b2, W3, b3, out);
}